// Round 1
// baseline (21577.991 us; speedup 1.0000x reference)
//
#include <hip/hip_runtime.h>
#include <cstdint>
#include <cstddef>

#define T_LEN 8192
#define EMB 256
#define HD 256          // hidden per direction
#define G4 1024         // 4*HD
#define NT 16
#define START_IX 14
#define STOP_IX 15

// ---------------------------------------------------------------------------
// Phase A: xw[dir][t][r] = emb[dir? T-1-t : t] @ w_ih^T + (b_ih + b_hh)
// grid (T/32, G4/128, 2), block 256
// ---------------------------------------------------------------------------
__global__ __launch_bounds__(256) void k_gemm_xw(
    const int* __restrict__ sent, const float* __restrict__ embed,
    const float* __restrict__ wih_f, const float* __restrict__ wih_b,
    const float* __restrict__ bih_f, const float* __restrict__ bhh_f,
    const float* __restrict__ bih_b, const float* __restrict__ bhh_b,
    float* __restrict__ xw)
{
    const int dir = blockIdx.z;
    const float* __restrict__ wih = dir ? wih_b : wih_f;
    const float* __restrict__ bih = dir ? bih_b : bih_f;
    const float* __restrict__ bhh = dir ? bhh_b : bhh_f;
    __shared__ float at[32][65];
    __shared__ float bt[128][65];
    const int t0 = blockIdx.x * 32, r0 = blockIdx.y * 128;
    const int tid = threadIdx.x;
    const int tx = tid & 31, ty = tid >> 5;
    float acc[4][4] = {};
    for (int k0 = 0; k0 < EMB; k0 += 64) {
        for (int i = tid; i < 32 * 64; i += 256) {
            int row = i >> 6, k = i & 63;
            int t = t0 + row;
            int ts = dir ? (T_LEN - 1 - t) : t;
            at[row][k] = embed[(size_t)sent[ts] * EMB + k0 + k];
        }
        for (int i = tid; i < 128 * 64; i += 256) {
            int row = i >> 6, k = i & 63;
            bt[row][k] = wih[(size_t)(r0 + row) * EMB + k0 + k];
        }
        __syncthreads();
#pragma unroll 16
        for (int kc = 0; kc < 64; ++kc) {
            float a[4], b[4];
#pragma unroll
            for (int u = 0; u < 4; ++u) a[u] = at[ty * 4 + u][kc];
#pragma unroll
            for (int u = 0; u < 4; ++u) b[u] = bt[tx * 4 + u][kc];
#pragma unroll
            for (int u = 0; u < 4; ++u)
#pragma unroll
                for (int v = 0; v < 4; ++v) acc[u][v] += a[u] * b[v];
        }
        __syncthreads();
    }
#pragma unroll
    for (int u = 0; u < 4; ++u) {
        int t = t0 + ty * 4 + u;
#pragma unroll
        for (int v = 0; v < 4; ++v) {
            int r = r0 + tx * 4 + v;
            xw[((size_t)dir * T_LEN + t) * G4 + r] = acc[u][v] + bih[r] + bhh[r];
        }
    }
}

// ---------------------------------------------------------------------------
// Phase B: the two LSTM scans. grid 16 (= dir*8 + w), block 512.
// WG w of a direction owns outputs j in [w*32, w*32+32) for all 4 gates:
// 128 rows of w_hh held register-resident (thread t: quarter q=t>>7, row
// r=t&127, 64 weights). Each step: partial dots -> LDS reduce -> gates ->
// c/h update by threads 0..31 -> h slice broadcast via agent-scope stores +
// per-(step,w) flag; all WGs poll 8 flags then reload full h into LDS.
// h_hist[dir][t][256] doubles as the hs output consumed by k_feats.
// ---------------------------------------------------------------------------
__global__ __launch_bounds__(512, 2) void k_lstm(
    const float* __restrict__ whh_f, const float* __restrict__ whh_b,
    const float* __restrict__ h0, const float* __restrict__ c0,
    const float* __restrict__ xw, float* h_hist, unsigned* flags)
{
    const int dir = blockIdx.x >> 3;
    const int w = blockIdx.x & 7;
    const float* __restrict__ whh = dir ? whh_b : whh_f;
    const int tid = threadIdx.x;
    const int q = tid >> 7;        // k-quarter 0..3
    const int r = tid & 127;       // local row 0..127
    const int gi = r >> 5, jj = r & 31;
    const int R = gi * 256 + w * 32 + jj;   // global row in [0,1024)

    __shared__ float h_lds[256];
    __shared__ float partial[512];
    __shared__ float act_lds[128];
    __shared__ float xw_lds[2][128];

    float4 wreg[16];
    {
        const float4* wp = (const float4*)&whh[(size_t)R * HD + q * 64];
#pragma unroll
        for (int u = 0; u < 16; ++u) wreg[u] = wp[u];
    }

    if (tid < 256) h_lds[tid] = h0[dir * HD + tid];
    float c = 0.f;
    if (tid < 32) c = c0[dir * HD + w * 32 + tid];
    if (tid < 128)
        xw_lds[0][tid] = xw[((size_t)dir * T_LEN) * G4 + gi * 256 + w * 32 + jj];
    __syncthreads();

    float* hh = h_hist + (size_t)dir * T_LEN * HD;
    unsigned* fl = flags + (size_t)dir * T_LEN * 8;

    for (int t = 0; t < T_LEN; ++t) {
        const int cur = t & 1, nxt = cur ^ 1;
        // prefetch next step's xw slice (latency hidden under matvec)
        float xwpre = 0.f;
        if (tid < 128 && t + 1 < T_LEN)
            xwpre = xw[((size_t)dir * T_LEN + (t + 1)) * G4 + gi * 256 + w * 32 + jj];

        // matvec partial: dot over this thread's k-quarter
        float accv = 0.f;
        const float4* hp = (const float4*)&h_lds[q * 64];
#pragma unroll
        for (int u = 0; u < 16; ++u) {
            float4 hv = hp[u];
            float4 wv = wreg[u];
            accv += wv.x * hv.x + wv.y * hv.y + wv.z * hv.z + wv.w * hv.w;
        }
        partial[q * 128 + r] = accv;
        __syncthreads();

        if (tid < 128) {
            float z = xw_lds[cur][tid] + partial[tid] + partial[128 + tid]
                    + partial[256 + tid] + partial[384 + tid];
            float a;
            if (gi == 2) a = tanhf(z);
            else         a = 1.f / (1.f + expf(-z));
            act_lds[tid] = a;
            xw_lds[nxt][tid] = xwpre;
        }
        __syncthreads();

        if (tid < 32) {
            float iv = act_lds[tid],      fv = act_lds[32 + tid];
            float gv = act_lds[64 + tid], ov = act_lds[96 + tid];
            c = fv * c + iv * gv;
            float hv = ov * tanhf(c);
            __hip_atomic_store(&hh[(size_t)t * HD + w * 32 + tid], hv,
                               __ATOMIC_RELAXED, __HIP_MEMORY_SCOPE_AGENT);
        }
        __syncthreads();   // drains vmcnt: h-slice stores are at coherence point
        if (tid == 0)
            __hip_atomic_store(&fl[t * 8 + w], 1u,
                               __ATOMIC_RELEASE, __HIP_MEMORY_SCOPE_AGENT);
        if (tid < 8) {
            int spin = 0;
            while (__hip_atomic_load(&fl[t * 8 + tid],
                                     __ATOMIC_ACQUIRE, __HIP_MEMORY_SCOPE_AGENT) == 0u) {
                if (++spin > (1 << 22)) break;   // safety: never hang the bench
            }
        }
        __syncthreads();
        if (tid < 256) {
            float hv = __hip_atomic_load(&hh[(size_t)t * HD + tid],
                                         __ATOMIC_RELAXED, __HIP_MEMORY_SCOPE_AGENT);
            h_lds[tid] = hv;
        }
        __syncthreads();
    }
}

// ---------------------------------------------------------------------------
// Phase C: feats[t][tag] = [hs_f[t], hs_b[t]] . W_out[tag] + b_out[tag]
// grid 512, block 256 (one thread per (t,tag))
// ---------------------------------------------------------------------------
__global__ __launch_bounds__(256) void k_feats(
    const float* __restrict__ h_hist, const float* __restrict__ Wout,
    const float* __restrict__ bout, float* __restrict__ feats)
{
    int idx = blockIdx.x * 256 + threadIdx.x;
    int tag = idx & 15, t = idx >> 4;
    const float4* hf = (const float4*)(h_hist + (size_t)t * HD);
    const float4* hb = (const float4*)(h_hist + (size_t)(T_LEN + (T_LEN - 1 - t)) * HD);
    const float4* w0 = (const float4*)(Wout + (size_t)tag * 512);
    const float4* w1 = w0 + 64;
    float acc = bout[tag];
    for (int k = 0; k < 64; ++k) {
        float4 a = hf[k], b = w0[k];
        acc += a.x * b.x + a.y * b.y + a.z * b.z + a.w * b.w;
    }
    for (int k = 0; k < 64; ++k) {
        float4 a = hb[k], b = w1[k];
        acc += a.x * b.x + a.y * b.y + a.z * b.z + a.w * b.w;
    }
    feats[(size_t)t * NT + tag] = acc;
}

// ---------------------------------------------------------------------------
// Phase D: Viterbi. 1 block, 256 threads.
// Forward: wave 0, fp64 fv (fv grows to ~1.5e4; fp32 ulp there ~1e-3 risks
// argmax flips). Lane l: i=l&15, jg=l>>4 covers j in [4jg,4jg+4).
// Backpointers stored as bytes. Backtrack: map-composition suffix scan
// (associative) over per-thread 32-step composites -> fully parallel.
// ---------------------------------------------------------------------------
__device__ __forceinline__ unsigned bsel16(uint4 g, unsigned e) {
    unsigned wd = (e < 8u) ? ((e < 4u) ? g.x : g.y) : ((e < 12u) ? g.z : g.w);
    return (wd >> ((e & 3u) * 8u)) & 15u;
}

__global__ __launch_bounds__(256) void k_viterbi(
    const float* __restrict__ feats, const float* __restrict__ trans,
    int* __restrict__ out, unsigned char* __restrict__ bp)
{
    __shared__ double fv[16];
    __shared__ int sid;
    __shared__ unsigned slo[512], shi[512];
    const int tid = threadIdx.x;

    if (tid < 64) {
        const int i = tid & 15, jg = tid >> 4;
        double tr[4];
#pragma unroll
        for (int u = 0; u < 4; ++u) tr[u] = (double)trans[i * 16 + jg * 4 + u];
        if (tid < 16) fv[tid] = (tid == START_IX) ? 0.0 : -10000.0;
        float fcur = (tid < 16) ? feats[i] : 0.f;

        for (int t = 0; t < T_LEN; ++t) {
            float fnext = 0.f;
            if (tid < 16 && t + 1 < T_LEN) fnext = feats[(size_t)(t + 1) * NT + i];

            double best = -1e300; int bj = 0;
#pragma unroll
            for (int u = 0; u < 4; ++u) {
                double v = fv[jg * 4 + u] + tr[u];
                if (v > best) { best = v; bj = jg * 4 + u; }   // ascending: first-max
            }
            // reduce across jg groups; jnp.argmax tie-break = smallest j
            {
                double ob = __shfl_down(best, 32); int oj = __shfl_down(bj, 32);
                if (ob > best || (ob == best && oj < bj)) { best = ob; bj = oj; }
                ob = __shfl_down(best, 16); oj = __shfl_down(bj, 16);
                if (ob > best || (ob == best && oj < bj)) { best = ob; bj = oj; }
            }
            if (tid < 16) {
                bp[(size_t)t * 16 + i] = (unsigned char)bj;
                fv[i] = (double)fcur + best;
            }
            fcur = fnext;
        }
        // terminal: fv + transition[:, STOP], argmax with first-max tie-break
        double term = (tid < 16) ? fv[tid] + (double)trans[tid * 16 + STOP_IX] : -1e300;
        int ti = tid;
#pragma unroll
        for (int off = 1; off < 16; off <<= 1) {
            double ov = __shfl_xor(term, off); int oi = __shfl_xor(ti, off);
            if (ov > term || (ov == term && oi < ti)) { term = ov; ti = oi; }
        }
        if (tid == 0) sid = ti;
    }
    __syncthreads();

    // ---- backtrack: suffix scan of composed backpointer maps ----
    const int j = tid;   // owns steps [32j, 32j+32)
    unsigned Flo = 0x76543210u, Fhi = 0xfedcba98u;   // identity map
    for (int t = 32 * j + 31; t >= 32 * j; --t) {
        uint4 g = *(const uint4*)&bp[(size_t)t * 16];
        unsigned nlo = 0, nhi = 0;
#pragma unroll
        for (int x = 0; x < 8; ++x) {
            unsigned e = (Flo >> (x * 4)) & 15u;
            nlo |= bsel16(g, e) << (x * 4);
        }
#pragma unroll
        for (int x = 0; x < 8; ++x) {
            unsigned e = (Fhi >> (x * 4)) & 15u;
            nhi |= bsel16(g, e) << (x * 4);
        }
        Flo = nlo; Fhi = nhi;
    }
    slo[j] = Flo; shi[j] = Fhi;
    slo[j + 256] = 0x76543210u; shi[j + 256] = 0xfedcba98u;  // identity pad
    __syncthreads();
    for (int off = 1; off < 256; off <<= 1) {
        unsigned alo = slo[j], ahi = shi[j];
        unsigned blo = slo[j + off], bhi = shi[j + off];
        __syncthreads();
        unsigned nlo = 0, nhi = 0;
#pragma unroll
        for (int x = 0; x < 8; ++x) {
            unsigned e = (blo >> (x * 4)) & 15u;
            unsigned rr = ((e < 8u ? alo : ahi) >> ((e & 7u) * 4u)) & 15u;
            nlo |= rr << (x * 4);
        }
#pragma unroll
        for (int x = 0; x < 8; ++x) {
            unsigned e = (bhi >> (x * 4)) & 15u;
            unsigned rr = ((e < 8u ? alo : ahi) >> ((e & 7u) * 4u)) & 15u;
            nhi |= rr << (x * 4);
        }
        slo[j] = nlo; shi[j] = nhi;
        __syncthreads();
    }
    // path[32j+31] = S_{32(j+1)}(id_last); then walk down within the block
    int idl = sid;
    unsigned plo = slo[j + 1], phi = shi[j + 1];
    unsigned x = (((unsigned)idl < 8u ? plo : phi) >> (((unsigned)idl & 7u) * 4u)) & 15u;
    out[32 * j + 31] = (int)x;
    for (int t = 32 * j + 30; t >= 32 * j; --t) {
        x = (unsigned)bp[(size_t)(t + 1) * 16 + x];
        out[t] = (int)x;
    }
}

// ---------------------------------------------------------------------------
extern "C" void kernel_launch(void* const* d_in, const int* in_sizes, int n_in,
                              void* d_out, int out_size, void* d_ws, size_t ws_size,
                              hipStream_t stream) {
    const int*   sent  = (const int*)  d_in[0];
    const float* embed = (const float*)d_in[1];
    const float* wih_f = (const float*)d_in[2];
    const float* whh_f = (const float*)d_in[3];
    const float* bih_f = (const float*)d_in[4];
    const float* bhh_f = (const float*)d_in[5];
    const float* wih_b = (const float*)d_in[6];
    const float* whh_b = (const float*)d_in[7];
    const float* bih_b = (const float*)d_in[8];
    const float* bhh_b = (const float*)d_in[9];
    const float* Wout  = (const float*)d_in[10];
    const float* bout  = (const float*)d_in[11];
    const float* trans = (const float*)d_in[12];
    const float* h0    = (const float*)d_in[13];
    const float* c0    = (const float*)d_in[14];
    int* out = (int*)d_out;

    // ws layout (fp32 elements unless noted); total ~81.3 MB
    float* ws_xw   = (float*)d_ws;                                  // 2*T*1024
    float* ws_h    = ws_xw + (size_t)2 * T_LEN * G4;                // 2*T*256
    float* ws_feat = ws_h + (size_t)2 * T_LEN * HD;                 // T*16
    unsigned* ws_flags = (unsigned*)(ws_feat + (size_t)T_LEN * NT); // 2*T*8 u32
    unsigned char* ws_bp = (unsigned char*)(ws_flags + (size_t)2 * T_LEN * 8); // T*16 B

    hipMemsetAsync(ws_flags, 0, (size_t)2 * T_LEN * 8 * sizeof(unsigned), stream);

    dim3 gA(T_LEN / 32, G4 / 128, 2);
    k_gemm_xw<<<gA, 256, 0, stream>>>(sent, embed, wih_f, wih_b,
                                      bih_f, bhh_f, bih_b, bhh_b, ws_xw);
    k_lstm<<<16, 512, 0, stream>>>(whh_f, whh_b, h0, c0, ws_xw, ws_h, ws_flags);
    k_feats<<<512, 256, 0, stream>>>(ws_h, Wout, bout, ws_feat);
    k_viterbi<<<1, 256, 0, stream>>>(ws_feat, trans, out, ws_bp);
}

// Round 2
// 18263.959 us; speedup vs baseline: 1.1815x; 1.1815x over previous
//
#include <hip/hip_runtime.h>
#include <cstdint>
#include <cstddef>

#define T_LEN 8192
#define EMB 256
#define HD 256          // hidden per direction
#define G4 1024         // 4*HD
#define NT 16
#define START_IX 14
#define STOP_IX 15

// ---------------------------------------------------------------------------
// Phase A: xw[dir][t][r] = emb[dir? T-1-t : t] @ w_ih^T + (b_ih + b_hh)
// grid (T/32, G4/128, 2), block 256   (unchanged from round 1 — correct)
// ---------------------------------------------------------------------------
__global__ __launch_bounds__(256) void k_gemm_xw(
    const int* __restrict__ sent, const float* __restrict__ embed,
    const float* __restrict__ wih_f, const float* __restrict__ wih_b,
    const float* __restrict__ bih_f, const float* __restrict__ bhh_f,
    const float* __restrict__ bih_b, const float* __restrict__ bhh_b,
    float* __restrict__ xw)
{
    const int dir = blockIdx.z;
    const float* __restrict__ wih = dir ? wih_b : wih_f;
    const float* __restrict__ bih = dir ? bih_b : bih_f;
    const float* __restrict__ bhh = dir ? bhh_b : bhh_f;
    __shared__ float at[32][65];
    __shared__ float bt[128][65];
    const int t0 = blockIdx.x * 32, r0 = blockIdx.y * 128;
    const int tid = threadIdx.x;
    const int tx = tid & 31, ty = tid >> 5;
    float acc[4][4] = {};
    for (int k0 = 0; k0 < EMB; k0 += 64) {
        for (int i = tid; i < 32 * 64; i += 256) {
            int row = i >> 6, k = i & 63;
            int t = t0 + row;
            int ts = dir ? (T_LEN - 1 - t) : t;
            at[row][k] = embed[(size_t)sent[ts] * EMB + k0 + k];
        }
        for (int i = tid; i < 128 * 64; i += 256) {
            int row = i >> 6, k = i & 63;
            bt[row][k] = wih[(size_t)(r0 + row) * EMB + k0 + k];
        }
        __syncthreads();
#pragma unroll 16
        for (int kc = 0; kc < 64; ++kc) {
            float a[4], b[4];
#pragma unroll
            for (int u = 0; u < 4; ++u) a[u] = at[ty * 4 + u][kc];
#pragma unroll
            for (int u = 0; u < 4; ++u) b[u] = bt[tx * 4 + u][kc];
#pragma unroll
            for (int u = 0; u < 4; ++u)
#pragma unroll
                for (int v = 0; v < 4; ++v) acc[u][v] += a[u] * b[v];
        }
        __syncthreads();
    }
#pragma unroll
    for (int u = 0; u < 4; ++u) {
        int t = t0 + ty * 4 + u;
#pragma unroll
        for (int v = 0; v < 4; ++v) {
            int r = r0 + tx * 4 + v;
            xw[((size_t)dir * T_LEN + t) * G4 + r] = acc[u][v] + bih[r] + bhh[r];
        }
    }
}

// ---------------------------------------------------------------------------
// Phase B: LSTM scans. grid 16 (= dir*8 + w), block 512.
// Sync redesign vs round 1: h_hist is pre-set to 0xFFFFFFFF (-NaN sentinel,
// unreachable from finite arithmetic). Producers store h words with relaxed
// agent-scope atomics; consumers poll the h words THEMSELVES (each dword is
// self-validating) -> 1 MALL RTT on the critical path instead of 3, and
// 2 barriers/step instead of 5.
// Thread roles per step (after B1):
//   tid 0..31    : reduce 16 partials, 4 gate activations, c/h update,
//                  store own h slice (issued before any poll in barrier order
//                  -> no circular wait)
//   tid 128..383 : poll the 7 remote h slices of this step -> h_lds
//   tid 384..511 : prefetch xw[t+1] -> xw_lds[nxt]
// ---------------------------------------------------------------------------
__global__ __launch_bounds__(512) void k_lstm(
    const float* __restrict__ whh_f, const float* __restrict__ whh_b,
    const float* __restrict__ h0, const float* __restrict__ c0,
    const float* __restrict__ xw, float* h_hist)
{
    const int dir = blockIdx.x >> 3;
    const int w = blockIdx.x & 7;
    const float* __restrict__ whh = dir ? whh_b : whh_f;
    const int tid = threadIdx.x;
    const int q = tid >> 7;        // k-quarter 0..3
    const int r = tid & 127;       // local row 0..127
    const int gi = r >> 5, jj = r & 31;
    const int R = gi * 256 + w * 32 + jj;   // global gate-row in [0,1024)

    __shared__ float h_lds[256];
    __shared__ float partial[512];
    __shared__ float xw_lds[2][128];

    float4 wreg[16];
    {
        const float4* wp = (const float4*)&whh[(size_t)R * HD + q * 64];
#pragma unroll
        for (int u = 0; u < 16; ++u) wreg[u] = wp[u];
    }

    if (tid < 256) h_lds[tid] = h0[dir * HD + tid];
    float c = 0.f;
    if (tid < 32) c = c0[dir * HD + w * 32 + tid];
    if (tid < 128)
        xw_lds[0][tid] = xw[((size_t)dir * T_LEN) * G4 + (tid >> 5) * 256 + w * 32 + (tid & 31)];
    __syncthreads();

    float* hh = h_hist + (size_t)dir * T_LEN * HD;

    for (int t = 0; t < T_LEN; ++t) {
        const int cur = t & 1, nxt = cur ^ 1;

        // matvec partial over this thread's k-quarter (h reads are wave-wide
        // same-address LDS broadcasts -> conflict-free)
        float accv = 0.f;
        const float4* hp = (const float4*)&h_lds[q * 64];
#pragma unroll
        for (int u = 0; u < 16; ++u) {
            float4 hv = hp[u];
            float4 wv = wreg[u];
            accv += wv.x * hv.x + wv.y * hv.y + wv.z * hv.z + wv.w * hv.w;
        }
        partial[q * 128 + r] = accv;
        __syncthreads();   // B1

        if (tid < 32) {
            // full reduce + gates + update on one wave slice: producer's
            // store issues ASAP, no intermediate barrier
            float zi = xw_lds[cur][tid]
                     + partial[0 * 128 + 0 * 32 + tid] + partial[1 * 128 + 0 * 32 + tid]
                     + partial[2 * 128 + 0 * 32 + tid] + partial[3 * 128 + 0 * 32 + tid];
            float zf = xw_lds[cur][32 + tid]
                     + partial[0 * 128 + 1 * 32 + tid] + partial[1 * 128 + 1 * 32 + tid]
                     + partial[2 * 128 + 1 * 32 + tid] + partial[3 * 128 + 1 * 32 + tid];
            float zg = xw_lds[cur][64 + tid]
                     + partial[0 * 128 + 2 * 32 + tid] + partial[1 * 128 + 2 * 32 + tid]
                     + partial[2 * 128 + 2 * 32 + tid] + partial[3 * 128 + 2 * 32 + tid];
            float zo = xw_lds[cur][96 + tid]
                     + partial[0 * 128 + 3 * 32 + tid] + partial[1 * 128 + 3 * 32 + tid]
                     + partial[2 * 128 + 3 * 32 + tid] + partial[3 * 128 + 3 * 32 + tid];
            float iv = 1.f / (1.f + expf(-zi));
            float fv = 1.f / (1.f + expf(-zf));
            float gv = tanhf(zg);
            float ov = 1.f / (1.f + expf(-zo));
            c = fv * c + iv * gv;
            float hv = ov * tanhf(c);
            __hip_atomic_store((unsigned*)&hh[(size_t)t * HD + w * 32 + tid],
                               __float_as_uint(hv),
                               __ATOMIC_RELAXED, __HIP_MEMORY_SCOPE_AGENT);
            h_lds[w * 32 + tid] = hv;
        } else if (tid >= 128 && tid < 384) {
            const int i = tid - 128;
            if ((i >> 5) != w) {
                const unsigned* src = (const unsigned*)&hh[(size_t)t * HD + i];
                unsigned v;
                int spin = 0;
                do {
                    v = __hip_atomic_load(src, __ATOMIC_RELAXED,
                                          __HIP_MEMORY_SCOPE_AGENT);
                } while (v == 0xFFFFFFFFu && ++spin < (1 << 18));  // safety cap
                h_lds[i] = __uint_as_float(v);
            }
        } else if (tid >= 384) {
            const int u = tid - 384;
            if (t + 1 < T_LEN)
                xw_lds[nxt][u] = xw[((size_t)dir * T_LEN + (t + 1)) * G4
                                    + (u >> 5) * 256 + w * 32 + (u & 31)];
        }
        __syncthreads();   // B2
    }
}

// ---------------------------------------------------------------------------
// Phase C: feats[t][tag] = [hs_f[t], hs_b[t]] . W_out[tag] + b_out[tag]
// ---------------------------------------------------------------------------
__global__ __launch_bounds__(256) void k_feats(
    const float* __restrict__ h_hist, const float* __restrict__ Wout,
    const float* __restrict__ bout, float* __restrict__ feats)
{
    int idx = blockIdx.x * 256 + threadIdx.x;
    int tag = idx & 15, t = idx >> 4;
    const float4* hf = (const float4*)(h_hist + (size_t)t * HD);
    const float4* hb = (const float4*)(h_hist + (size_t)(T_LEN + (T_LEN - 1 - t)) * HD);
    const float4* w0 = (const float4*)(Wout + (size_t)tag * 512);
    const float4* w1 = w0 + 64;
    float acc = bout[tag];
    for (int k = 0; k < 64; ++k) {
        float4 a = hf[k], b = w0[k];
        acc += a.x * b.x + a.y * b.y + a.z * b.z + a.w * b.w;
    }
    for (int k = 0; k < 64; ++k) {
        float4 a = hb[k], b = w1[k];
        acc += a.x * b.x + a.y * b.y + a.z * b.z + a.w * b.w;
    }
    feats[(size_t)t * NT + tag] = acc;
}

// ---------------------------------------------------------------------------
// Phase D: Viterbi (unchanged from round 1 — bit-exact path).
// ---------------------------------------------------------------------------
__device__ __forceinline__ unsigned bsel16(uint4 g, unsigned e) {
    unsigned wd = (e < 8u) ? ((e < 4u) ? g.x : g.y) : ((e < 12u) ? g.z : g.w);
    return (wd >> ((e & 3u) * 8u)) & 15u;
}

__global__ __launch_bounds__(256) void k_viterbi(
    const float* __restrict__ feats, const float* __restrict__ trans,
    int* __restrict__ out, unsigned char* __restrict__ bp)
{
    __shared__ double fv[16];
    __shared__ int sid;
    __shared__ unsigned slo[512], shi[512];
    const int tid = threadIdx.x;

    if (tid < 64) {
        const int i = tid & 15, jg = tid >> 4;
        double tr[4];
#pragma unroll
        for (int u = 0; u < 4; ++u) tr[u] = (double)trans[i * 16 + jg * 4 + u];
        if (tid < 16) fv[tid] = (tid == START_IX) ? 0.0 : -10000.0;
        float fcur = (tid < 16) ? feats[i] : 0.f;

        for (int t = 0; t < T_LEN; ++t) {
            float fnext = 0.f;
            if (tid < 16 && t + 1 < T_LEN) fnext = feats[(size_t)(t + 1) * NT + i];

            double best = -1e300; int bj = 0;
#pragma unroll
            for (int u = 0; u < 4; ++u) {
                double v = fv[jg * 4 + u] + tr[u];
                if (v > best) { best = v; bj = jg * 4 + u; }   // ascending: first-max
            }
            {
                double ob = __shfl_down(best, 32); int oj = __shfl_down(bj, 32);
                if (ob > best || (ob == best && oj < bj)) { best = ob; bj = oj; }
                ob = __shfl_down(best, 16); oj = __shfl_down(bj, 16);
                if (ob > best || (ob == best && oj < bj)) { best = ob; bj = oj; }
            }
            if (tid < 16) {
                bp[(size_t)t * 16 + i] = (unsigned char)bj;
                fv[i] = (double)fcur + best;
            }
            fcur = fnext;
        }
        double term = (tid < 16) ? fv[tid] + (double)trans[tid * 16 + STOP_IX] : -1e300;
        int ti = tid;
#pragma unroll
        for (int off = 1; off < 16; off <<= 1) {
            double ov = __shfl_xor(term, off); int oi = __shfl_xor(ti, off);
            if (ov > term || (ov == term && oi < ti)) { term = ov; ti = oi; }
        }
        if (tid == 0) sid = ti;
    }
    __syncthreads();

    // backtrack: suffix scan of composed backpointer maps
    const int j = tid;
    unsigned Flo = 0x76543210u, Fhi = 0xfedcba98u;
    for (int t = 32 * j + 31; t >= 32 * j; --t) {
        uint4 g = *(const uint4*)&bp[(size_t)t * 16];
        unsigned nlo = 0, nhi = 0;
#pragma unroll
        for (int x = 0; x < 8; ++x) {
            unsigned e = (Flo >> (x * 4)) & 15u;
            nlo |= bsel16(g, e) << (x * 4);
        }
#pragma unroll
        for (int x = 0; x < 8; ++x) {
            unsigned e = (Fhi >> (x * 4)) & 15u;
            nhi |= bsel16(g, e) << (x * 4);
        }
        Flo = nlo; Fhi = nhi;
    }
    slo[j] = Flo; shi[j] = Fhi;
    slo[j + 256] = 0x76543210u; shi[j + 256] = 0xfedcba98u;
    __syncthreads();
    for (int off = 1; off < 256; off <<= 1) {
        unsigned alo = slo[j], ahi = shi[j];
        unsigned blo = slo[j + off], bhi = shi[j + off];
        __syncthreads();
        unsigned nlo = 0, nhi = 0;
#pragma unroll
        for (int x = 0; x < 8; ++x) {
            unsigned e = (blo >> (x * 4)) & 15u;
            unsigned rr = ((e < 8u ? alo : ahi) >> ((e & 7u) * 4u)) & 15u;
            nlo |= rr << (x * 4);
        }
#pragma unroll
        for (int x = 0; x < 8; ++x) {
            unsigned e = (bhi >> (x * 4)) & 15u;
            unsigned rr = ((e < 8u ? alo : ahi) >> ((e & 7u) * 4u)) & 15u;
            nhi |= rr << (x * 4);
        }
        slo[j] = nlo; shi[j] = nhi;
        __syncthreads();
    }
    int idl = sid;
    unsigned plo = slo[j + 1], phi = shi[j + 1];
    unsigned x = (((unsigned)idl < 8u ? plo : phi) >> (((unsigned)idl & 7u) * 4u)) & 15u;
    out[32 * j + 31] = (int)x;
    for (int t = 32 * j + 30; t >= 32 * j; --t) {
        x = (unsigned)bp[(size_t)(t + 1) * 16 + x];
        out[t] = (int)x;
    }
}

// ---------------------------------------------------------------------------
extern "C" void kernel_launch(void* const* d_in, const int* in_sizes, int n_in,
                              void* d_out, int out_size, void* d_ws, size_t ws_size,
                              hipStream_t stream) {
    const int*   sent  = (const int*)  d_in[0];
    const float* embed = (const float*)d_in[1];
    const float* wih_f = (const float*)d_in[2];
    const float* whh_f = (const float*)d_in[3];
    const float* bih_f = (const float*)d_in[4];
    const float* bhh_f = (const float*)d_in[5];
    const float* wih_b = (const float*)d_in[6];
    const float* whh_b = (const float*)d_in[7];
    const float* bih_b = (const float*)d_in[8];
    const float* bhh_b = (const float*)d_in[9];
    const float* Wout  = (const float*)d_in[10];
    const float* bout  = (const float*)d_in[11];
    const float* trans = (const float*)d_in[12];
    const float* h0    = (const float*)d_in[13];
    const float* c0    = (const float*)d_in[14];
    int* out = (int*)d_out;

    float* ws_xw   = (float*)d_ws;                                  // 2*T*1024
    float* ws_h    = ws_xw + (size_t)2 * T_LEN * G4;                // 2*T*256
    float* ws_feat = ws_h + (size_t)2 * T_LEN * HD;                 // T*16
    unsigned char* ws_bp = (unsigned char*)(ws_feat + (size_t)T_LEN * NT); // T*16 B

    // sentinel-fill h_hist: 0xFFFFFFFF == -NaN, unreachable from finite math.
    // Re-set every launch -> no reliance on cross-call buffer state.
    hipMemsetAsync(ws_h, 0xFF, (size_t)2 * T_LEN * HD * sizeof(float), stream);

    dim3 gA(T_LEN / 32, G4 / 128, 2);
    k_gemm_xw<<<gA, 256, 0, stream>>>(sent, embed, wih_f, wih_b,
                                      bih_f, bhh_f, bih_b, bhh_b, ws_xw);
    k_lstm<<<16, 512, 0, stream>>>(whh_f, whh_b, h0, c0, ws_xw, ws_h);
    k_feats<<<512, 256, 0, stream>>>(ws_h, Wout, bout, ws_feat);
    k_viterbi<<<1, 256, 0, stream>>>(ws_feat, trans, out, ws_bp);
}